// Round 8
// baseline (180.783 us; speedup 1.0000x reference)
//
#include <hip/hip_runtime.h>
#include <hip/hip_bf16.h>

#define N_NODES 50000
#define N_PAD   50048   // 391 * 128
#define N_EDGES 150000
#define F 512
#define BM 128
#define BN 128
#define BK 64
#define NBLK 196        // ceil(50000/256)
#define NWG  1564       // 391 * 4 gemm blocks

typedef __attribute__((ext_vector_type(4))) float f32x4;
typedef __attribute__((ext_vector_type(4))) unsigned int u32x4;
typedef __attribute__((ext_vector_type(2))) unsigned int u32x2;

__device__ __forceinline__ unsigned short f2bf(float f) {
    unsigned int u = __float_as_uint(f);
    return (unsigned short)((u + 0x7fffu + ((u >> 16) & 1u)) >> 16);
}
__device__ __forceinline__ unsigned int pack2(float a, float b) {
    return (unsigned int)f2bf(a) | ((unsigned int)f2bf(b) << 16);
}
__device__ __forceinline__ void gload16(const void* g, void* l) {
    __builtin_amdgcn_global_load_lds(
        (const __attribute__((address_space(1))) unsigned int*)g,
        (__attribute__((address_space(3))) unsigned int*)l, 16, 0, 0);
}

// ---- degree histograms ----
__global__ void __launch_bounds__(256) crd_deg(const int* __restrict__ src,
                                               const int* __restrict__ dst,
                                               int* __restrict__ hist) {
    int e = blockIdx.x * 256 + threadIdx.x;
    if (e < N_EDGES) {
        atomicAdd(&hist[src[e]], 1);
        atomicAdd(&hist[N_NODES + dst[e]], 1);
    }
}

__global__ void __launch_bounds__(256) crd_norm(const int* __restrict__ hist,
                                                float* __restrict__ norms) {
    int i = blockIdx.x * 256 + threadIdx.x;
    if (i < 2 * N_NODES) {
        int d = hist[i];
        norms[i] = rsqrtf((float)(d > 0 ? d : 1));
    }
}

// ---- hierarchical exclusive scan of deg_in ----
__global__ void __launch_bounds__(256) crd_bsum(const int* __restrict__ hist_in,
                                                int* __restrict__ bsum) {
    __shared__ int s[256];
    int t = threadIdx.x;
    int i = blockIdx.x * 256 + t;
    s[t] = (i < N_NODES) ? hist_in[i] : 0;
    __syncthreads();
    #pragma unroll
    for (int o = 128; o > 0; o >>= 1) {
        if (t < o) s[t] += s[t + o];
        __syncthreads();
    }
    if (t == 0) bsum[blockIdx.x] = s[0];
}

__global__ void __launch_bounds__(256) crd_bscan(const int* __restrict__ bsum,
                                                 int* __restrict__ bsumoff) {
    __shared__ int s[256];
    int t = threadIdx.x;
    int v = (t < NBLK) ? bsum[t] : 0;
    s[t] = v;
    __syncthreads();
    #pragma unroll
    for (int d = 1; d < 256; d <<= 1) {
        int add = (t >= d) ? s[t - d] : 0;
        __syncthreads();
        s[t] += add;
        __syncthreads();
    }
    if (t < NBLK) bsumoff[t] = s[t] - v;
}

__global__ void __launch_bounds__(256) crd_escan(const int* __restrict__ hist_in,
                                                 const int* __restrict__ bsumoff,
                                                 int* __restrict__ off,
                                                 int* __restrict__ cursor) {
    __shared__ int s[256];
    int t = threadIdx.x;
    int i = blockIdx.x * 256 + t;
    int v = (i < N_NODES) ? hist_in[i] : 0;
    s[t] = v;
    __syncthreads();
    #pragma unroll
    for (int d = 1; d < 256; d <<= 1) {
        int add = (t >= d) ? s[t - d] : 0;
        __syncthreads();
        s[t] += add;
        __syncthreads();
    }
    int excl = s[t] - v + bsumoff[blockIdx.x];
    if (i < N_NODES) { off[i] = excl; cursor[i] = excl; }
    if (i == N_NODES - 1) off[N_NODES] = excl + v;
}

__global__ void __launch_bounds__(256) crd_place(const int* __restrict__ src,
                                                 const int* __restrict__ dst,
                                                 int* __restrict__ cursor,
                                                 int* __restrict__ sorted) {
    int e = blockIdx.x * 256 + threadIdx.x;
    if (e < N_EDGES) {
        int slot = atomicAdd(&cursor[dst[e]], 1);
        sorted[slot] = src[e];
    }
}

__global__ void __launch_bounds__(256) crd_wt(const float* __restrict__ W,
                                              unsigned short* __restrict__ Wt) {
    int idx = blockIdx.x * 256 + threadIdx.x;
    int n = idx >> 9, k = idx & 511;
    Wt[idx] = f2bf(W[k * F + n]);
}

// ---- xb = bf16(x * norm_src), 8 elems/thread (rows 0..N_NODES) ----
__global__ void __launch_bounds__(256) crd_xb(const float* __restrict__ x,
                                              const float* __restrict__ norms,
                                              unsigned short* __restrict__ xb) {
    int t = blockIdx.x * 256 + threadIdx.x;
    size_t i = (size_t)t * 8;
    float ns = norms[t >> 6];
    f32x4 v0 = *(const f32x4*)(x + i);
    f32x4 v1 = *(const f32x4*)(x + i + 4);
    v0 *= ns; v1 *= ns;
    u32x4 w;
    w.x = pack2(v0.x, v0.y); w.y = pack2(v0.z, v0.w);
    w.z = pack2(v1.x, v1.y); w.w = pack2(v1.z, v1.w);
    *(u32x4*)(xb + i) = w;
}

__device__ __forceinline__ void acc8(float* a, u32x4 v) {
    a[0] += __uint_as_float(v.x << 16); a[1] += __uint_as_float(v.x & 0xffff0000u);
    a[2] += __uint_as_float(v.y << 16); a[3] += __uint_as_float(v.y & 0xffff0000u);
    a[4] += __uint_as_float(v.z << 16); a[5] += __uint_as_float(v.z & 0xffff0000u);
    a[6] += __uint_as_float(v.w << 16); a[7] += __uint_as_float(v.w & 0xffff0000u);
}

// ---- reorder-path gather: out[d] = relu(norm_dst[d] * sum H[src] + bias) ----
// H rows are bf16 1KB, L3-resident; out write coalesced f32.
__global__ void __launch_bounds__(256) crd_gout(const unsigned short* __restrict__ H,
                                                const int* __restrict__ sorted,
                                                const int* __restrict__ off,
                                                const float* __restrict__ norms,
                                                const float* __restrict__ bias,
                                                float* __restrict__ out) {
    int wid = (blockIdx.x * 256 + threadIdx.x) >> 6;
    int lane = threadIdx.x & 63;
    if (wid >= N_NODES) return;
    float a[8] = {0.f,0.f,0.f,0.f,0.f,0.f,0.f,0.f};
    float b[8] = {0.f,0.f,0.f,0.f,0.f,0.f,0.f,0.f};
    int e0 = off[wid], e1 = off[wid + 1];
    int e = e0;
    for (; e + 1 < e1; e += 2) {
        int s0 = sorted[e], s1 = sorted[e + 1];
        u32x4 v0 = *(const u32x4*)(H + (size_t)s0 * F + lane * 8);
        u32x4 v1 = *(const u32x4*)(H + (size_t)s1 * F + lane * 8);
        acc8(a, v0);
        acc8(b, v1);
    }
    if (e < e1) {
        u32x4 v = *(const u32x4*)(H + (size_t)sorted[e] * F + lane * 8);
        acc8(a, v);
    }
    float nd = norms[N_NODES + wid];
    f32x4 bv0 = *(const f32x4*)(bias + lane * 8);
    f32x4 bv1 = *(const f32x4*)(bias + lane * 8 + 4);
    f32x4 o0, o1;
    o0.x = fmaxf((a[0] + b[0]) * nd + bv0.x, 0.f);
    o0.y = fmaxf((a[1] + b[1]) * nd + bv0.y, 0.f);
    o0.z = fmaxf((a[2] + b[2]) * nd + bv0.z, 0.f);
    o0.w = fmaxf((a[3] + b[3]) * nd + bv0.w, 0.f);
    o1.x = fmaxf((a[4] + b[4]) * nd + bv1.x, 0.f);
    o1.y = fmaxf((a[5] + b[5]) * nd + bv1.y, 0.f);
    o1.z = fmaxf((a[6] + b[6]) * nd + bv1.z, 0.f);
    o1.w = fmaxf((a[7] + b[7]) * nd + bv1.w, 0.f);
    float* po = out + (size_t)wid * F + lane * 8;
    *(f32x4*)po = o0;
    *(f32x4*)(po + 4) = o1;
}

// ---- fallback-path gather (r7): aggb[d] = bf16(norm_dst * sum x[src]*norm_src) ----
__global__ void __launch_bounds__(256) crd_gather(const float* __restrict__ x,
                                                  const int* __restrict__ sorted,
                                                  const int* __restrict__ off,
                                                  const float* __restrict__ norms,
                                                  unsigned short* __restrict__ aggb) {
    int wid = (blockIdx.x * 256 + threadIdx.x) >> 6;
    int lane = threadIdx.x & 63;
    if (wid >= N_PAD) return;
    f32x4 a0 = {0.f,0.f,0.f,0.f}, a1 = a0, b0 = a0, b1 = a0;
    if (wid < N_NODES) {
        int e0 = off[wid], e1 = off[wid + 1];
        int e = e0;
        for (; e + 1 < e1; e += 2) {
            int s0 = sorted[e], s1 = sorted[e + 1];
            float ns0 = norms[s0], ns1 = norms[s1];
            const f32x4* p0 = (const f32x4*)(x + (size_t)s0 * F);
            const f32x4* p1 = (const f32x4*)(x + (size_t)s1 * F);
            a0 += p0[lane] * ns0;  a1 += p0[64 + lane] * ns0;
            b0 += p1[lane] * ns1;  b1 += p1[64 + lane] * ns1;
        }
        if (e < e1) {
            int s = sorted[e];
            float ns = norms[s];
            const f32x4* p = (const f32x4*)(x + (size_t)s * F);
            a0 += p[lane] * ns;  a1 += p[64 + lane] * ns;
        }
        float nd = norms[N_NODES + wid];
        a0 = (a0 + b0) * nd;
        a1 = (a1 + b1) * nd;
    }
    unsigned short* row = aggb + (size_t)wid * F;
    u32x2 w0, w1;
    w0.x = pack2(a0.x, a0.y); w0.y = pack2(a0.z, a0.w);
    w1.x = pack2(a1.x, a1.y); w1.y = pack2(a1.z, a1.w);
    *(u32x2*)(row + lane * 4) = w0;
    *(u32x2*)(row + 256 + lane * 4) = w1;
}

// ---- GEMM (r7-proven structure): D = A_tile @ Wt^T via swapped-operand MFMA.
// TO_BF16=1: store D as bf16 H (no bias/relu, pad rows harmless).
// TO_BF16=0: store relu(D + bias) as f32 out (fallback).
template <int TO_BF16>
__global__ void __launch_bounds__(256, 3) crd_gemm(const unsigned short* __restrict__ A,
                                                   const unsigned short* __restrict__ Wt,
                                                   const float* __restrict__ bias,
                                                   void* __restrict__ outp) {
    __shared__ __align__(16) unsigned short lA[8 * BM * 8];   // 16 KB
    __shared__ __align__(16) unsigned short lB[8 * BN * 8];   // 16 KB
    const int tid = threadIdx.x;
    // XCD-bijective swizzle (r4/r7-proven: FETCH 104->29 MB)
    int bid = blockIdx.x;
    int xcd = bid & 7, lid = bid >> 3;
    int swz = (xcd < 4 ? xcd * 196 : 784 + (xcd - 4) * 195) + lid;
    const int rowbase = (swz >> 2) * BM;
    const int nbase = (swz & 3) * BN;
    const int lane = tid & 63;
    const int wave = tid >> 6;
    const int wm = wave >> 1, wn = wave & 1;
    const int g = lane >> 4, r = lane & 15;

    f32x4 acc[4][4];
    #pragma unroll
    for (int i = 0; i < 4; ++i)
        #pragma unroll
        for (int j = 0; j < 4; ++j) acc[i][j] = (f32x4){0.f, 0.f, 0.f, 0.f};

    for (int ks = 0; ks < F / BK; ++ks) {
        #pragma unroll
        for (int j = 0; j < 4; ++j) {
            int gg = (wave * 4 + j) * 64 + lane;
            int k8 = gg >> 7, row = gg & 127;
            gload16(A + (size_t)(rowbase + row) * F + ks * BK + k8 * 8,
                    &lA[(size_t)(wave * 4 + j) * 64 * 8]);
        }
        #pragma unroll
        for (int j = 0; j < 4; ++j) {
            int gg = (wave * 4 + j) * 64 + lane;
            int k8 = gg >> 7, n = gg & 127;
            gload16(Wt + (size_t)(nbase + n) * F + ks * BK + k8 * 8,
                    &lB[(size_t)(wave * 4 + j) * 64 * 8]);
        }
        __syncthreads();
        #pragma unroll
        for (int kk = 0; kk < 2; ++kk) {
            int k8 = kk * 4 + g;
            u32x4 af[4], bfr[4];
            #pragma unroll
            for (int mi = 0; mi < 4; ++mi)
                af[mi] = *(const u32x4*)&lA[(k8 * BM + wm * 64 + mi * 16 + r) * 8];
            #pragma unroll
            for (int ni = 0; ni < 4; ++ni)
                bfr[ni] = *(const u32x4*)&lB[(k8 * BN + wn * 64 + ni * 16 + r) * 8];
            #pragma unroll
            for (int mi = 0; mi < 4; ++mi)
                #pragma unroll
                for (int ni = 0; ni < 4; ++ni)
                    asm("v_mfma_f32_16x16x32_bf16 %0, %1, %2, %0"
                        : "+v"(acc[mi][ni]) : "v"(bfr[ni]), "v"(af[mi]));   // swapped
        }
        __syncthreads();
    }
    // D[n][m]: lane m = l&15; n-quad base = ni*16 + g*4 (4 consecutive n per acc)
    #pragma unroll
    for (int mi = 0; mi < 4; ++mi) {
        int row = rowbase + wm * 64 + mi * 16 + r;
        if (TO_BF16) {
            unsigned short* H = (unsigned short*)outp;
            #pragma unroll
            for (int ni = 0; ni < 4; ++ni) {
                int c0 = nbase + wn * 64 + ni * 16 + g * 4;
                u32x2 w;
                w.x = pack2(acc[mi][ni].x, acc[mi][ni].y);
                w.y = pack2(acc[mi][ni].z, acc[mi][ni].w);
                *(u32x2*)(H + (size_t)row * F + c0) = w;
            }
        } else if (row < N_NODES) {
            float* out = (float*)outp;
            #pragma unroll
            for (int ni = 0; ni < 4; ++ni) {
                int c0 = nbase + wn * 64 + ni * 16 + g * 4;
                f32x4 bv = *(const f32x4*)(bias + c0);
                f32x4 v = acc[mi][ni] + bv;
                v.x = fmaxf(v.x, 0.f); v.y = fmaxf(v.y, 0.f);
                v.z = fmaxf(v.z, 0.f); v.w = fmaxf(v.w, 0.f);
                *(f32x4*)(out + (size_t)row * F + c0) = v;
            }
        }
    }
}

extern "C" void kernel_launch(void* const* d_in, const int* in_sizes, int n_in,
                              void* d_out, int out_size, void* d_ws, size_t ws_size,
                              hipStream_t stream) {
    const float* x = (const float*)d_in[0];
    const int* src = (const int*)d_in[1];
    const int* dst = (const int*)d_in[2];
    const float* W = (const float*)d_in[3];
    const float* bias = (const float*)d_in[4];
    float* out = (float*)d_out;

    // small buffers first so the fallback path needs no H slot
    float* norms = (float*)d_ws;                                // 2N f32
    int* hist = (int*)(norms + 2 * N_NODES);                    // 2N int
    int* off = hist + 2 * N_NODES;                              // N+1 int
    int* cursor = off + N_NODES + 1;                            // N int
    int* sorted = cursor + N_NODES;                             // E int
    int* bsum = sorted + N_EDGES;                               // NBLK int
    int* bsumoff = bsum + NBLK;                                 // NBLK int
    unsigned short* Wt = (unsigned short*)
        (((uintptr_t)(bsumoff + NBLK) + 63) & ~(uintptr_t)63);  // F*F bf16
    unsigned short* xb = Wt + (size_t)F * F;                    // N_PAD*F bf16 (or aggb)
    unsigned short* H  = xb + (size_t)N_PAD * F;                // N_PAD*F bf16 (reorder)
    size_t need_min = (size_t)((char*)(xb + (size_t)N_PAD * F) - (char*)d_ws);
    size_t need_big = (size_t)((char*)(H  + (size_t)N_PAD * F) - (char*)d_ws);
    if (ws_size < need_min) {
        hipMemsetAsync(d_out, 0, (size_t)out_size * sizeof(float), stream);
        return;
    }
    const bool reorder = (ws_size >= need_big);

    hipMemsetAsync(hist, 0, 2 * N_NODES * sizeof(int), stream);
    crd_deg<<<(N_EDGES + 255) / 256, 256, 0, stream>>>(src, dst, hist);
    crd_norm<<<(2 * N_NODES + 255) / 256, 256, 0, stream>>>(hist, norms);
    crd_wt<<<(F * F) / 256, 256, 0, stream>>>(W, Wt);
    crd_bsum<<<NBLK, 256, 0, stream>>>(hist + N_NODES, bsum);
    crd_bscan<<<1, 256, 0, stream>>>(bsum, bsumoff);
    crd_escan<<<NBLK, 256, 0, stream>>>(hist + N_NODES, bsumoff, off, cursor);
    crd_place<<<(N_EDGES + 255) / 256, 256, 0, stream>>>(src, dst, cursor, sorted);

    if (reorder) {
        // H = (x*norm_src) @ W  (bf16), then gather H -> out with bias+relu
        crd_xb<<<(int)(((size_t)N_NODES * F / 8) / 256), 256, 0, stream>>>(x, norms, xb);
        crd_gemm<1><<<NWG, 256, 0, stream>>>(xb, Wt, bias, H);
        crd_gout<<<N_NODES * 64 / 256, 256, 0, stream>>>(H, sorted, off, norms, bias, out);
    } else {
        // fallback: aggregate x then GEMM -> out (r7 pipeline), aggb aliases xb
        crd_gather<<<N_PAD / 4, 256, 0, stream>>>(x, sorted, off, norms, xb);
        crd_gemm<0><<<NWG, 256, 0, stream>>>(xb, Wt, bias, out);
    }
}

// Round 10
// 165.059 us; speedup vs baseline: 1.0953x; 1.0953x over previous
//
#include <hip/hip_runtime.h>
#include <hip/hip_bf16.h>

#define N_NODES 50000
#define N_PAD   50048   // 391 * 128
#define N_EDGES 150000
#define F 512
#define BM 128
#define BN 128
#define BK 64
#define NBLK 196        // ceil(50000/256)
#define NWG  1564       // 391 * 4 gemm blocks

typedef __attribute__((ext_vector_type(4))) float f32x4;
typedef __attribute__((ext_vector_type(4))) unsigned int u32x4;
typedef __attribute__((ext_vector_type(2))) unsigned int u32x2;

__device__ __forceinline__ unsigned short f2bf(float f) {
    unsigned int u = __float_as_uint(f);
    return (unsigned short)((u + 0x7fffu + ((u >> 16) & 1u)) >> 16);
}
__device__ __forceinline__ unsigned int pack2(float a, float b) {
    return (unsigned int)f2bf(a) | ((unsigned int)f2bf(b) << 16);
}
__device__ __forceinline__ void gload16(const void* g, void* l) {
    __builtin_amdgcn_global_load_lds(
        (const __attribute__((address_space(1))) unsigned int*)g,
        (__attribute__((address_space(3))) unsigned int*)l, 16, 0, 0);
}

// ---- degree histograms ----
__global__ void __launch_bounds__(256) crd_deg(const int* __restrict__ src,
                                               const int* __restrict__ dst,
                                               int* __restrict__ hist) {
    int e = blockIdx.x * 256 + threadIdx.x;
    if (e < N_EDGES) {
        atomicAdd(&hist[src[e]], 1);
        atomicAdd(&hist[N_NODES + dst[e]], 1);
    }
}

__global__ void __launch_bounds__(256) crd_norm(const int* __restrict__ hist,
                                                float* __restrict__ norms) {
    int i = blockIdx.x * 256 + threadIdx.x;
    if (i < 2 * N_NODES) {
        int d = hist[i];
        norms[i] = rsqrtf((float)(d > 0 ? d : 1));
    }
}

// ---- hierarchical exclusive scan of deg_in ----
__global__ void __launch_bounds__(256) crd_bsum(const int* __restrict__ hist_in,
                                                int* __restrict__ bsum) {
    __shared__ int s[256];
    int t = threadIdx.x;
    int i = blockIdx.x * 256 + t;
    s[t] = (i < N_NODES) ? hist_in[i] : 0;
    __syncthreads();
    #pragma unroll
    for (int o = 128; o > 0; o >>= 1) {
        if (t < o) s[t] += s[t + o];
        __syncthreads();
    }
    if (t == 0) bsum[blockIdx.x] = s[0];
}

__global__ void __launch_bounds__(256) crd_bscan(const int* __restrict__ bsum,
                                                 int* __restrict__ bsumoff) {
    __shared__ int s[256];
    int t = threadIdx.x;
    int v = (t < NBLK) ? bsum[t] : 0;
    s[t] = v;
    __syncthreads();
    #pragma unroll
    for (int d = 1; d < 256; d <<= 1) {
        int add = (t >= d) ? s[t - d] : 0;
        __syncthreads();
        s[t] += add;
        __syncthreads();
    }
    if (t < NBLK) bsumoff[t] = s[t] - v;
}

__global__ void __launch_bounds__(256) crd_escan(const int* __restrict__ hist_in,
                                                 const int* __restrict__ bsumoff,
                                                 int* __restrict__ off,
                                                 int* __restrict__ cursor) {
    __shared__ int s[256];
    int t = threadIdx.x;
    int i = blockIdx.x * 256 + t;
    int v = (i < N_NODES) ? hist_in[i] : 0;
    s[t] = v;
    __syncthreads();
    #pragma unroll
    for (int d = 1; d < 256; d <<= 1) {
        int add = (t >= d) ? s[t - d] : 0;
        __syncthreads();
        s[t] += add;
        __syncthreads();
    }
    int excl = s[t] - v + bsumoff[blockIdx.x];
    if (i < N_NODES) { off[i] = excl; cursor[i] = excl; }
    if (i == N_NODES - 1) off[N_NODES] = excl + v;
}

__global__ void __launch_bounds__(256) crd_place(const int* __restrict__ src,
                                                 const int* __restrict__ dst,
                                                 int* __restrict__ cursor,
                                                 int* __restrict__ sorted) {
    int e = blockIdx.x * 256 + threadIdx.x;
    if (e < N_EDGES) {
        int slot = atomicAdd(&cursor[dst[e]], 1);
        sorted[slot] = src[e];
    }
}

__global__ void __launch_bounds__(256) crd_wt(const float* __restrict__ W,
                                              unsigned short* __restrict__ Wt) {
    int idx = blockIdx.x * 256 + threadIdx.x;
    int n = idx >> 9, k = idx & 511;
    Wt[idx] = f2bf(W[k * F + n]);
}

// ---- gather: 2 waves per dst node, each owns a 256-float half-row ----
// aggb[d] = bf16(norm_dst[d] * sum_e x[src_e]*norm_src); pad rows -> 0.
// Math identical to the r7-proven 1-wave gather (same f32 accumulation,
// same single bf16 rounding) -- only the row is split across 2 waves.
__global__ void __launch_bounds__(256) crd_gather(const float* __restrict__ x,
                                                  const int* __restrict__ sorted,
                                                  const int* __restrict__ off,
                                                  const float* __restrict__ norms,
                                                  unsigned short* __restrict__ aggb) {
    int gw = (blockIdx.x * 256 + threadIdx.x) >> 6;   // global wave id
    int lane = threadIdx.x & 63;
    int wid = gw >> 1, half = gw & 1;
    if (wid >= N_PAD) return;
    f32x4 a = {0.f,0.f,0.f,0.f}, b = a;
    if (wid < N_NODES) {
        int e0 = off[wid], e1 = off[wid + 1];
        const float* xh = x + half * 256;
        int e = e0;
        for (; e + 1 < e1; e += 2) {                  // 2-edge unroll (ILP)
            int s0 = sorted[e], s1 = sorted[e + 1];
            float ns0 = norms[s0], ns1 = norms[s1];
            a += ((const f32x4*)(xh + (size_t)s0 * F))[lane] * ns0;
            b += ((const f32x4*)(xh + (size_t)s1 * F))[lane] * ns1;
        }
        if (e < e1) {
            int s = sorted[e];
            a += ((const f32x4*)(xh + (size_t)s * F))[lane] * norms[s];
        }
        float nd = norms[N_NODES + wid];
        a = (a + b) * nd;
    }
    u32x2 w;
    w.x = pack2(a.x, a.y); w.y = pack2(a.z, a.w);
    *(u32x2*)(aggb + (size_t)wid * F + half * 256 + lane * 4) = w;
}

// ---- out = relu(aggb @ W + b): EXACT r7-proven GEMM (unchanged) ----
// Swapped-operand MFMA: D[n][m]; lane m = l&15, n-quad = (l>>4)*4.
__global__ void __launch_bounds__(256, 3) crd_gemm(const unsigned short* __restrict__ aggb,
                                                   const unsigned short* __restrict__ Wt,
                                                   const float* __restrict__ bias,
                                                   float* __restrict__ out) {
    __shared__ __align__(16) unsigned short lA[8 * BM * 8];   // 16 KB
    __shared__ __align__(16) unsigned short lB[8 * BN * 8];   // 16 KB
    const int tid = threadIdx.x;
    // XCD-bijective swizzle (r4/r7-proven: FETCH 104->29 MB)
    int bid = blockIdx.x;
    int xcd = bid & 7, lid = bid >> 3;
    int swz = (xcd < 4 ? xcd * 196 : 784 + (xcd - 4) * 195) + lid;
    const int rowbase = (swz >> 2) * BM;
    const int nbase = (swz & 3) * BN;
    const int lane = tid & 63;
    const int wave = tid >> 6;
    const int wm = wave >> 1, wn = wave & 1;
    const int g = lane >> 4, r = lane & 15;

    f32x4 acc[4][4];
    #pragma unroll
    for (int i = 0; i < 4; ++i)
        #pragma unroll
        for (int j = 0; j < 4; ++j) acc[i][j] = (f32x4){0.f, 0.f, 0.f, 0.f};

    for (int ks = 0; ks < F / BK; ++ks) {
        #pragma unroll
        for (int j = 0; j < 4; ++j) {
            int gg = (wave * 4 + j) * 64 + lane;
            int k8 = gg >> 7, row = gg & 127;
            gload16(aggb + (size_t)(rowbase + row) * F + ks * BK + k8 * 8,
                    &lA[(size_t)(wave * 4 + j) * 64 * 8]);
        }
        #pragma unroll
        for (int j = 0; j < 4; ++j) {
            int gg = (wave * 4 + j) * 64 + lane;
            int k8 = gg >> 7, n = gg & 127;
            gload16(Wt + (size_t)(nbase + n) * F + ks * BK + k8 * 8,
                    &lB[(size_t)(wave * 4 + j) * 64 * 8]);
        }
        __syncthreads();
        #pragma unroll
        for (int kk = 0; kk < 2; ++kk) {
            int k8 = kk * 4 + g;
            u32x4 af[4], bfr[4];
            #pragma unroll
            for (int mi = 0; mi < 4; ++mi)
                af[mi] = *(const u32x4*)&lA[(k8 * BM + wm * 64 + mi * 16 + r) * 8];
            #pragma unroll
            for (int ni = 0; ni < 4; ++ni)
                bfr[ni] = *(const u32x4*)&lB[(k8 * BN + wn * 64 + ni * 16 + r) * 8];
            #pragma unroll
            for (int mi = 0; mi < 4; ++mi)
                #pragma unroll
                for (int ni = 0; ni < 4; ++ni)
                    asm("v_mfma_f32_16x16x32_bf16 %0, %1, %2, %0"
                        : "+v"(acc[mi][ni]) : "v"(bfr[ni]), "v"(af[mi]));   // swapped
        }
        __syncthreads();
    }
    #pragma unroll
    for (int mi = 0; mi < 4; ++mi) {
        int row = rowbase + wm * 64 + mi * 16 + r;
        if (row < N_NODES) {
            #pragma unroll
            for (int ni = 0; ni < 4; ++ni) {
                int c0 = nbase + wn * 64 + ni * 16 + g * 4;
                f32x4 bv = *(const f32x4*)(bias + c0);
                f32x4 v = acc[mi][ni] + bv;
                v.x = fmaxf(v.x, 0.f); v.y = fmaxf(v.y, 0.f);
                v.z = fmaxf(v.z, 0.f); v.w = fmaxf(v.w, 0.f);
                *(f32x4*)(out + (size_t)row * F + c0) = v;
            }
        }
    }
}

extern "C" void kernel_launch(void* const* d_in, const int* in_sizes, int n_in,
                              void* d_out, int out_size, void* d_ws, size_t ws_size,
                              hipStream_t stream) {
    const float* x = (const float*)d_in[0];
    const int* src = (const int*)d_in[1];
    const int* dst = (const int*)d_in[2];
    const float* W = (const float*)d_in[3];
    const float* bias = (const float*)d_in[4];
    float* out = (float*)d_out;

    float* norms = (float*)d_ws;                                // 2N f32
    int* hist = (int*)(norms + 2 * N_NODES);                    // 2N int
    int* off = hist + 2 * N_NODES;                              // N+1 int
    int* cursor = off + N_NODES + 1;                            // N int
    int* sorted = cursor + N_NODES;                             // E int
    int* bsum = sorted + N_EDGES;                               // NBLK int
    int* bsumoff = bsum + NBLK;                                 // NBLK int
    unsigned short* Wt = (unsigned short*)
        (((uintptr_t)(bsumoff + NBLK) + 63) & ~(uintptr_t)63);  // F*F bf16
    unsigned short* aggb = Wt + (size_t)F * F;                  // N_PAD*F bf16
    size_t need = (size_t)((char*)(aggb + (size_t)N_PAD * F) - (char*)d_ws);
    if (ws_size < need) {
        hipMemsetAsync(d_out, 0, (size_t)out_size * sizeof(float), stream);
        return;
    }

    hipMemsetAsync(hist, 0, 2 * N_NODES * sizeof(int), stream);
    crd_deg<<<(N_EDGES + 255) / 256, 256, 0, stream>>>(src, dst, hist);
    crd_norm<<<(2 * N_NODES + 255) / 256, 256, 0, stream>>>(hist, norms);
    crd_wt<<<(F * F) / 256, 256, 0, stream>>>(W, Wt);
    crd_bsum<<<NBLK, 256, 0, stream>>>(hist + N_NODES, bsum);
    crd_bscan<<<1, 256, 0, stream>>>(bsum, bsumoff);
    crd_escan<<<NBLK, 256, 0, stream>>>(hist + N_NODES, bsumoff, off, cursor);
    crd_place<<<(N_EDGES + 255) / 256, 256, 0, stream>>>(src, dst, cursor, sorted);
    crd_gather<<<N_PAD / 2, 256, 0, stream>>>(x, sorted, off, norms, aggb);
    crd_gemm<<<NWG, 256, 0, stream>>>(aggb, Wt, bias, out);
}